// Round 18
// baseline (119.700 us; speedup 1.0000x reference)
//
#include <hip/hip_runtime.h>
#include <math.h>

#define B_SZ 2
#define L_SEQ 2048
#define H_SZ 1024
#define NH 16
#define HD 64
#define QSCALE 0.18033688011112042f   // 0.125 * log2(e): S in log2 domain

typedef __attribute__((ext_vector_type(8))) short frag_ab;      // 8 bf16 = 4 VGPR
typedef __attribute__((ext_vector_type(4))) float frag_cd;      // 4 f32 acc
typedef __attribute__((ext_vector_type(8))) unsigned short u16x8;
typedef __attribute__((ext_vector_type(4))) unsigned short u16x4;

__device__ __forceinline__ unsigned short f2bf(float f) {
  unsigned int x = __builtin_bit_cast(unsigned int, f);
  x += 0x7fffu + ((x >> 16) & 1u);          // RNE
  return (unsigned short)(x >> 16);
}
__device__ __forceinline__ float bf2f(unsigned int u) {
  return __builtin_bit_cast(float, u << 16);
}
__device__ __forceinline__ unsigned int cvt_pk_bf16(float lo, float hi) {
  unsigned int r;
  asm("v_cvt_pk_bf16_f32 %0, %1, %2" : "=v"(r) : "v"(lo), "v"(hi));
  return r;
}
// async global->LDS, 16B per lane; LDS dest must be linear in lane order
__device__ __forceinline__ void gload16(const void* g, void* l) {
  __builtin_amdgcn_global_load_lds((const __attribute__((address_space(1))) void*)g,
                                   (__attribute__((address_space(3))) void*)l, 16, 0, 0);
}

__device__ __forceinline__ void cvt8(const float* __restrict__ in,
                                     unsigned short* __restrict__ out, int i) {
  float4 a = *(const float4*)&in[i];
  float4 b = *(const float4*)&in[i + 4];
  u16x8 o = {f2bf(a.x), f2bf(a.y), f2bf(a.z), f2bf(a.w),
             f2bf(b.x), f2bf(b.y), f2bf(b.z), f2bf(b.w)};
  *(u16x8*)&out[i] = o;
}

// BK=32 LDS bank-quad swizzle (R16-validated: conflicts 3.1M -> 0)
#define SWZ32(row) ((((row) >> 1) & 3) << 3)

// ---------------------------------------------------------------------------
// glue_pre: [0,256) rope table TRANSPOSED [j][l] | [256,2304) cvt x
//         | [2304,3840) cvt w_qkv | [3840,4352) cvt w_out.
// ---------------------------------------------------------------------------
__global__ __launch_bounds__(256) void glue_pre_k(
    const float* __restrict__ x, const float* __restrict__ wq, const float* __restrict__ wo,
    unsigned short* __restrict__ xb, unsigned short* __restrict__ wqb,
    unsigned short* __restrict__ wob, float2* __restrict__ ctab) {
  int bx = blockIdx.x, tid = threadIdx.x;
  if (bx < 256) {
    int idx = bx * 256 + tid;          // idx = j*2048 + l
    int j = idx >> 11, l = idx & 2047;
    int ti = l >> 8;
    int s = l & 255;
    float ang_s;
    if (j < 16) ang_s = (float)(s & 15) * powf(10000.f, -(float)j / 16.f);
    else        ang_s = (float)(s >> 4) * powf(10000.f, -(float)(j - 16) / 16.f);
    float ang_t = (float)ti * powf(10000.f, -(float)j / 32.f);
    float a = ang_s + ang_t;
    ctab[idx] = make_float2(cosf(a), sinf(a));
  } else if (bx < 2304) {
    cvt8(x, xb, ((bx - 256) * 256 + tid) * 8);
  } else if (bx < 3840) {
    cvt8(wq, wqb, ((bx - 2304) * 256 + tid) * 8);
  } else {
    cvt8(wo, wob, ((bx - 3840) * 256 + tid) * 8);
  }
}

// staging with pre-swizzled global source (linear LDS dest, rule-21 pair)
#define G_ISSUE(k0, bi)                                                        \
  _Pragma("unroll") for (int it = 0; it < 2; ++it) {                           \
    int c = tid + it * 256;                                                    \
    int row = c >> 2, e0 = ((c & 3) * 8) ^ SWZ32(row);                         \
    gload16(A + (size_t)(m0 + row) * K + (k0) + e0, &As[bi][c * 8]);           \
    gload16(W + (size_t)(n0 + row) * K + (k0) + e0, &Ws[bi][c * 8]);           \
  }

// ---------------------------------------------------------------------------
// Fused QKV GEMM. Per-wave-uniform region => q/k halves computed TRANSPOSED
// (mfma(wf,af): D rows = features, cols = tokens) so each lane holds 4
// consecutive d -> RoPE pairs are in-register and stores are 1 u16x4 per
// frag (4x fewer store issues). V half keeps normal orientation (l-contig).
// Outputs: Qb,Kb [b][n][l][d] (q pre-scaled by QSCALE), Vt [b][n][d][l].
// ---------------------------------------------------------------------------
__global__ __launch_bounds__(256) void gemm_qkv_fused_k(
    const unsigned short* __restrict__ A, const unsigned short* __restrict__ W,
    const float* __restrict__ bias, const float2* __restrict__ ctab,
    unsigned short* __restrict__ Qb, unsigned short* __restrict__ Kb,
    unsigned short* __restrict__ Vt) {
  const int K = 1024, N = 3072;
  __shared__ unsigned short As[2][128 * 32];
  __shared__ unsigned short Ws[2][128 * 32];
  const frag_cd fzero = {0.f, 0.f, 0.f, 0.f};
  int tid = threadIdx.x;
  int nbx = N >> 7;
  int nwg = gridDim.x;
  int bid = blockIdx.x;
  int qq = nwg >> 3;
  int bidx = (bid & 7) * qq + (bid >> 3);    // bijective XCD-contiguous remap
  int m0 = (bidx / nbx) * 128, n0 = (bidx % nbx) * 128;
  int w = tid >> 6, lane = tid & 63, t = lane & 15, g = lane >> 4;
  int wm = w >> 1, wn = w & 1;
  int fsw = (8 * g) ^ SWZ32(t);              // frag elem offset
  int cbh = n0 + wn * 64;                    // this wave's 64-col half
  int regionw = (cbh >> 6) % 3;              // 0=q 1=k 2=v (wave-uniform)
  int head = cbh / 192;
  frag_cd acc[4][4];
#pragma unroll
  for (int mi = 0; mi < 4; ++mi)
#pragma unroll
    for (int ni = 0; ni < 4; ++ni) acc[mi][ni] = fzero;

  G_ISSUE(0, 0);
  __syncthreads();
  int kb = 0;
  for (int k0 = 0; k0 < K; k0 += 32, kb ^= 1) {
    if (k0 + 32 < K) { G_ISSUE(k0 + 32, kb ^ 1); }
    frag_ab af[4], wf[4];
#pragma unroll
    for (int mi = 0; mi < 4; ++mi)
      af[mi] = *(const frag_ab*)&As[kb][(wm * 64 + mi * 16 + t) * 32 + fsw];
#pragma unroll
    for (int ni = 0; ni < 4; ++ni)
      wf[ni] = *(const frag_ab*)&Ws[kb][(wn * 64 + ni * 16 + t) * 32 + fsw];
    __builtin_amdgcn_s_setprio(1);
    if (regionw != 2) {                      // q/k: transposed orientation
#pragma unroll
      for (int mi = 0; mi < 4; ++mi)
#pragma unroll
        for (int ni = 0; ni < 4; ++ni)
          acc[mi][ni] = __builtin_amdgcn_mfma_f32_16x16x32_bf16(wf[ni], af[mi], acc[mi][ni], 0, 0, 0);
    } else {                                 // v: normal orientation
#pragma unroll
      for (int mi = 0; mi < 4; ++mi)
#pragma unroll
        for (int ni = 0; ni < 4; ++ni)
          acc[mi][ni] = __builtin_amdgcn_mfma_f32_16x16x32_bf16(af[mi], wf[ni], acc[mi][ni], 0, 0, 0);
    }
    __builtin_amdgcn_s_setprio(0);
    __syncthreads();
  }

  // ---- fused epilogue ----
  if (regionw == 2) {
    // V (normal orientation): lane holds rows=tokens g*4+r, col=d ni*16+t.
#pragma unroll
    for (int ni = 0; ni < 4; ++ni) {
      int d = ni * 16 + t;
      float bv = bias[cbh + ni * 16 + t];
#pragma unroll
      for (int mi = 0; mi < 4; ++mi) {
        int row0 = m0 + wm * 64 + mi * 16 + g * 4;
        int bb = row0 >> 11, l0 = row0 & 2047;
        u16x4 ov;
#pragma unroll
        for (int r = 0; r < 4; ++r) ov[r] = f2bf(acc[mi][ni][r] + bv);
        *(u16x4*)&Vt[((size_t)((bb * NH + head) * HD + d)) * L_SEQ + l0] = ov;
      }
    }
  } else {
    // Q/K (transposed): lane holds features dd0..dd0+3 of token t.
    float qs = (regionw == 0) ? QSCALE : 1.f;
    unsigned short* dst = (regionw == 0) ? Qb : Kb;
#pragma unroll
    for (int ni = 0; ni < 4; ++ni) {
      int dd0 = ni * 16 + g * 4;             // within-head d base (cbh&63==0)
      float bv0 = bias[cbh + dd0];
      float bv1 = bias[cbh + dd0 + 1];
      float bv2 = bias[cbh + dd0 + 2];
      float bv3 = bias[cbh + dd0 + 3];
      const float2* c0 = ctab + (size_t)(dd0 >> 1) * 2048;
      const float2* c1 = c0 + 2048;
#pragma unroll
      for (int mi = 0; mi < 4; ++mi) {
        int m = m0 + wm * 64 + mi * 16 + t;
        int bb = m >> 11, ll = m & 2047;
        float2 cs0 = c0[ll];
        float2 cs1 = c1[ll];
        float v0 = acc[mi][ni][0] + bv0;
        float v1 = acc[mi][ni][1] + bv1;
        float v2 = acc[mi][ni][2] + bv2;
        float v3 = acc[mi][ni][3] + bv3;
        u16x4 ov;
        ov[0] = f2bf((v0 * cs0.x - v1 * cs0.y) * qs);
        ov[1] = f2bf((v0 * cs0.y + v1 * cs0.x) * qs);
        ov[2] = f2bf((v2 * cs1.x - v3 * cs1.y) * qs);
        ov[3] = f2bf((v2 * cs1.y + v3 * cs1.x) * qs);
        *(u16x4*)&dst[((size_t)((bb * NH + head) * L_SEQ + ll)) * HD + dd0] = ov;
      }
    }
  }
}

// ---------------------------------------------------------------------------
// Out-projection GEMM, 64x128 tile (grid 512 = 2 blocks/CU), fp32 out.
// All-swapped orientation: lane holds 4 consecutive out-features of one
// token -> float4 stores (4x fewer store issues).
// ---------------------------------------------------------------------------
__global__ __launch_bounds__(256) void gemm_out_k(
    const unsigned short* __restrict__ A, const unsigned short* __restrict__ W,
    const float* __restrict__ bias, float* __restrict__ C, int M, int N, int K) {
  __shared__ unsigned short As[2][64 * 32];
  __shared__ unsigned short Ws[2][128 * 32];
  const frag_cd fzero = {0.f, 0.f, 0.f, 0.f};
  int tid = threadIdx.x;
  int nbx = N >> 7;
  int nwg = gridDim.x;
  int bid = blockIdx.x;
  int qq = nwg >> 3;
  int bidx = (bid & 7) * qq + (bid >> 3);
  int m0 = (bidx / nbx) * 64, n0 = (bidx % nbx) * 128;
  int w = tid >> 6, lane = tid & 63, t = lane & 15, g = lane >> 4;
  int wm = w >> 1, wn = w & 1;
  int fsw = (8 * g) ^ SWZ32(t);
  frag_cd acc[2][4];
#pragma unroll
  for (int mi = 0; mi < 2; ++mi)
#pragma unroll
    for (int ni = 0; ni < 4; ++ni) acc[mi][ni] = fzero;

#define G_ISSUE2(k0, bi)                                                       \
  {                                                                            \
    int rowA = tid >> 2, e0A = ((tid & 3) * 8) ^ SWZ32(rowA);                  \
    gload16(A + (size_t)(m0 + rowA) * K + (k0) + e0A, &As[bi][tid * 8]);       \
    _Pragma("unroll") for (int it = 0; it < 2; ++it) {                         \
      int c = tid + it * 256;                                                  \
      int row = c >> 2, e0 = ((c & 3) * 8) ^ SWZ32(row);                       \
      gload16(W + (size_t)(n0 + row) * K + (k0) + e0, &Ws[bi][c * 8]);         \
    }                                                                          \
  }

  G_ISSUE2(0, 0);
  __syncthreads();
  int kb = 0;
  for (int k0 = 0; k0 < K; k0 += 32, kb ^= 1) {
    if (k0 + 32 < K) { G_ISSUE2(k0 + 32, kb ^ 1); }
    frag_ab af[2], wf[4];
#pragma unroll
    for (int mi = 0; mi < 2; ++mi)
      af[mi] = *(const frag_ab*)&As[kb][(wm * 32 + mi * 16 + t) * 32 + fsw];
#pragma unroll
    for (int ni = 0; ni < 4; ++ni)
      wf[ni] = *(const frag_ab*)&Ws[kb][(wn * 64 + ni * 16 + t) * 32 + fsw];
    __builtin_amdgcn_s_setprio(1);
#pragma unroll
    for (int mi = 0; mi < 2; ++mi)
#pragma unroll
      for (int ni = 0; ni < 4; ++ni)
        acc[mi][ni] = __builtin_amdgcn_mfma_f32_16x16x32_bf16(wf[ni], af[mi], acc[mi][ni], 0, 0, 0);
    __builtin_amdgcn_s_setprio(0);
    __syncthreads();
  }
  // epilogue (swapped): lane holds features ncol0..+3 of token m
#pragma unroll
  for (int mi = 0; mi < 2; ++mi)
#pragma unroll
    for (int ni = 0; ni < 4; ++ni) {
      int ncol = n0 + wn * 64 + ni * 16 + g * 4;
      int m = m0 + wm * 32 + mi * 16 + t;
      float4 o = {acc[mi][ni][0] + bias[ncol],
                  acc[mi][ni][1] + bias[ncol + 1],
                  acc[mi][ni][2] + bias[ncol + 2],
                  acc[mi][ni][3] + bias[ncol + 3]};
      *(float4*)&C[(size_t)m * N + ncol] = o;
    }
}

// ---------------------------------------------------------------------------
// MFMA flash attention (causal), DUAL-CHAIN 4-wave blocks (R17 green form).
// ---------------------------------------------------------------------------
__global__ __launch_bounds__(256) void attn_mfma_k(
    const unsigned short* __restrict__ Qg, const unsigned short* __restrict__ Kg,
    const unsigned short* __restrict__ Vt, unsigned short* __restrict__ Og) {
  __shared__ unsigned short Ks[2][64 * 64];
  __shared__ unsigned short Vs[2][64 * 64];
  __shared__ unsigned short PsL[4][16 * 64];
  __shared__ unsigned short PsS[4][16 * 64];
  const frag_cd fzero = {0.f, 0.f, 0.f, 0.f};
  const frag_cd cinit = {-32.f, -32.f, -32.f, -32.f};
  int bx = blockIdx.x;
  int qtA = bx & 15;
  int n = (bx >> 4) & 15;
  int b = bx >> 8;
  int qtB = 31 - qtA;
  int tid = threadIdx.x;
  int w = tid >> 6, lane = tid & 63, t = lane & 15, g = lane >> 4;
  size_t kvbase = ((size_t)(b * NH + n)) * L_SEQ * HD;
  int qrowL = qtB * 64 + w * 16 + t;
  int qrowS = qtA * 64 + w * 16 + t;
  unsigned short* pwL = &PsL[w][0];
  unsigned short* pwS = &PsS[w][0];

  const unsigned short* qpL = Qg + kvbase + (size_t)qrowL * HD;
  const unsigned short* qpS = Qg + kvbase + (size_t)qrowS * HD;
  frag_ab qfL0 = *(const frag_ab*)(qpL + 8 * g), qfL1 = *(const frag_ab*)(qpL + 32 + 8 * g);
  frag_ab qfS0 = *(const frag_ab*)(qpS + 8 * g), qfS1 = *(const frag_ab*)(qpS + 32 + 8 * g);

  frag_cd oaccL[4], oaccS[4];
#pragma unroll
  for (int db = 0; db < 4; ++db) { oaccL[db] = fzero; oaccS[db] = fzero; }
  float lLp = 0.f, lSp = 0.f;

  // staging: 256 threads, two 16B K chunks + two 16B V chunks each
  int srow = tid >> 3, se0 = (tid & 7) * 8;
  int sd0 = (srow * 64 + se0) ^ ((srow & 7) << 3);
  int sd1 = ((srow + 32) * 64 + se0) ^ ((srow & 7) << 3);
  u16x8 kreg0 = *(const u16x8*)(Kg + kvbase + (size_t)srow * HD + se0);
  u16x8 kreg1 = *(const u16x8*)(Kg + kvbase + (size_t)(srow + 32) * HD + se0);
  u16x8 vreg0 = *(const u16x8*)(Vt + kvbase + (size_t)srow * L_SEQ + se0);
  u16x8 vreg1 = *(const u16x8*)(Vt + kvbase + (size_t)(srow + 32) * L_SEQ + se0);
  *(u16x8*)&Ks[0][sd0] = kreg0;
  *(u16x8*)&Ks[0][sd1] = kreg1;
  *(u16x8*)&Vs[0][sd0] = vreg0;
  *(u16x8*)&Vs[0][sd1] = vreg1;
  if (qtB > 0) {
    kreg0 = *(const u16x8*)(Kg + kvbase + (size_t)(64 + srow) * HD + se0);
    kreg1 = *(const u16x8*)(Kg + kvbase + (size_t)(96 + srow) * HD + se0);
    vreg0 = *(const u16x8*)(Vt + kvbase + (size_t)srow * L_SEQ + 64 + se0);
    vreg1 = *(const u16x8*)(Vt + kvbase + (size_t)(srow + 32) * L_SEQ + 64 + se0);
  }

  for (int kt = 0; kt <= qtB; ++kt) {
    int cur = kt & 1, nxt = cur ^ 1;
    __syncthreads();
    if (kt < qtB) {                       // write-early: stage kt+1 at phase top
      *(u16x8*)&Ks[nxt][sd0] = kreg0;
      *(u16x8*)&Ks[nxt][sd1] = kreg1;
      *(u16x8*)&Vs[nxt][sd0] = vreg0;
      *(u16x8*)&Vs[nxt][sd1] = vreg1;
    }
    if (kt + 1 < qtB) {                   // issue loads for kt+2 (hide under compute)
      kreg0 = *(const u16x8*)(Kg + kvbase + (size_t)((kt + 2) * 64 + srow) * HD + se0);
      kreg1 = *(const u16x8*)(Kg + kvbase + (size_t)((kt + 2) * 64 + 32 + srow) * HD + se0);
      vreg0 = *(const u16x8*)(Vt + kvbase + (size_t)srow * L_SEQ + (kt + 2) * 64 + se0);
      vreg1 = *(const u16x8*)(Vt + kvbase + (size_t)(srow + 32) * L_SEQ + (kt + 2) * 64 + se0);
    }
    bool doS = (kt <= qtA);

    // shared K fragments
    frag_ab k0f[4], k1f[4];
#pragma unroll
    for (int kb = 0; kb < 4; ++kb) {
      k0f[kb] = *(const frag_ab*)&Ks[cur][(((kb * 16 + t) * 64) + 8 * g) ^ ((t & 7) << 3)];
      k1f[kb] = *(const frag_ab*)&Ks[cur][(((kb * 16 + t) * 64) + 32 + 8 * g) ^ ((t & 7) << 3)];
    }
    // QK for both chains (independent MFMA streams)
    frag_cd stL[4], stS[4];
    __builtin_amdgcn_s_setprio(1);
#pragma unroll
    for (int kb = 0; kb < 4; ++kb) {
      stL[kb] = __builtin_amdgcn_mfma_f32_16x16x32_bf16(k0f[kb], qfL0, cinit, 0, 0, 0);
      stL[kb] = __builtin_amdgcn_mfma_f32_16x16x32_bf16(k1f[kb], qfL1, stL[kb], 0, 0, 0);
    }
    if (doS) {
#pragma unroll
      for (int kb = 0; kb < 4; ++kb) {
        stS[kb] = __builtin_amdgcn_mfma_f32_16x16x32_bf16(k0f[kb], qfS0, cinit, 0, 0, 0);
        stS[kb] = __builtin_amdgcn_mfma_f32_16x16x32_bf16(k1f[kb], qfS1, stS[kb], 0, 0, 0);
      }
    }
    __builtin_amdgcn_s_setprio(0);

    // V fragments issue early (latency under softmax VALU)
    frag_ab v0f[4], v1f[4];
#pragma unroll
    for (int db = 0; db < 4; ++db) {
      v0f[db] = *(const frag_ab*)&Vs[cur][(((db * 16 + t) * 64) + 8 * g) ^ ((t & 7) << 3)];
      v1f[db] = *(const frag_ab*)&Vs[cur][(((db * 16 + t) * 64) + 32 + 8 * g) ^ ((t & 7) << 3)];
    }

    // softmax L -> PsL
    {
      bool diag = (kt == qtB);
      unsigned int pk[8];
#pragma unroll
      for (int i = 0; i < 8; ++i) {
        int kb = i >> 1, r0 = (2 * i) & 3;
        float x0 = stL[kb][r0], x1 = stL[kb][r0 + 1];
        if (diag) {
          if ((kt * 64 + kb * 16 + g * 4 + r0) > qrowL) x0 = -1e30f;
          if ((kt * 64 + kb * 16 + g * 4 + r0 + 1) > qrowL) x1 = -1e30f;
        }
        float p0 = __builtin_amdgcn_exp2f(x0);
        float p1 = __builtin_amdgcn_exp2f(x1);
        lLp += p0 + p1;
        pk[i] = cvt_pk_bf16(p0, p1);
      }
#pragma unroll
      for (int kb = 0; kb < 4; ++kb) {
        uint2 pr = {pk[kb * 2], pk[kb * 2 + 1]};
        *(uint2*)&pwL[(t * 64 + kb * 16 + g * 4) ^ ((t & 7) << 3)] = pr;
      }
    }
    // softmax S -> PsS (overlaps pwL read latency below)
    if (doS) {
      bool diag = (kt == qtA);
      unsigned int pk[8];
#pragma unroll
      for (int i = 0; i < 8; ++i) {
        int kb = i >> 1, r0 = (2 * i) & 3;
        float x0 = stS[kb][r0], x1 = stS[kb][r0 + 1];
        if (diag) {
          if ((kt * 64 + kb * 16 + g * 4 + r0) > qrowS) x0 = -1e30f;
          if ((kt * 64 + kb * 16 + g * 4 + r0 + 1) > qrowS) x1 = -1e30f;
        }
        float p0 = __builtin_amdgcn_exp2f(x0);
        float p1 = __builtin_amdgcn_exp2f(x1);
        lSp += p0 + p1;
        pk[i] = cvt_pk_bf16(p0, p1);
      }
#pragma unroll
      for (int kb = 0; kb < 4; ++kb) {
        uint2 pr = {pk[kb * 2], pk[kb * 2 + 1]};
        *(uint2*)&pwS[(t * 64 + kb * 16 + g * 4) ^ ((t & 7) << 3)] = pr;
      }
    }

    // PV_L (pfS read latency hides under these MFMAs)
    {
      frag_ab pf0 = *(const frag_ab*)&pwL[(t * 64 + 8 * g) ^ ((t & 7) << 3)];
      frag_ab pf1 = *(const frag_ab*)&pwL[(t * 64 + 32 + 8 * g) ^ ((t & 7) << 3)];
      __builtin_amdgcn_s_setprio(1);
#pragma unroll
      for (int db = 0; db < 4; ++db) {
        oaccL[db] = __builtin_amdgcn_mfma_f32_16x16x32_bf16(v0f[db], pf0, oaccL[db], 0, 0, 0);
        oaccL[db] = __builtin_amdgcn_mfma_f32_16x16x32_bf16(v1f[db], pf1, oaccL[db], 0, 0, 0);
      }
      __builtin_amdgcn_s_setprio(0);
    }
    if (doS) {
      frag_ab pf0 = *(const frag_ab*)&pwS[(t * 64 + 8 * g) ^ ((t & 7) << 3)];
      frag_ab pf1 = *(const frag_ab*)&pwS[(t * 64 + 32 + 8 * g) ^ ((t & 7) << 3)];
      __builtin_amdgcn_s_setprio(1);
#pragma unroll
      for (int db = 0; db < 4; ++db) {
        oaccS[db] = __builtin_amdgcn_mfma_f32_16x16x32_bf16(v0f[db], pf0, oaccS[db], 0, 0, 0);
        oaccS[db] = __builtin_amdgcn_mfma_f32_16x16x32_bf16(v1f[db], pf1, oaccS[db], 0, 0, 0);
      }
      __builtin_amdgcn_s_setprio(0);
    }
  }

  // epilogue: deferred l reduce, o = silu(O/l), both chains
  size_t ob0 = (size_t)b * L_SEQ * H_SZ + n * 64;
#pragma unroll
  for (int side = 0; side < 2; ++side) {
    float lp = side ? lSp : lLp;
    float l_run = lp + __shfl_xor(lp, 16);
    l_run += __shfl_xor(l_run, 32);
    float inv = 1.f / l_run;
    frag_cd* oacc = side ? oaccS : oaccL;
    int qrow = side ? qrowS : qrowL;
#pragma unroll
    for (int db = 0; db < 4; ++db) {
      u16x4 ov;
#pragma unroll
      for (int r = 0; r < 4; ++r) {
        float o = oacc[db][r] * inv;
        o = o / (1.f + __expf(-o));
        ov[r] = f2bf(o);
      }
      *(u16x4*)&Og[ob0 + (size_t)qrow * H_SZ + db * 16 + g * 4] = ov;
    }
  }
}

// ---------------------------------------------------------------------------
extern "C" void kernel_launch(void* const* d_in, const int* in_sizes, int n_in,
                              void* d_out, int out_size, void* d_ws, size_t ws_size,
                              hipStream_t stream) {
  const float* x = (const float*)d_in[0];
  const float* w_qkv = (const float*)d_in[1];
  const float* b_qkv = (const float*)d_in[2];
  const float* w_out = (const float*)d_in[3];
  const float* b_out = (const float*)d_in[4];
  float* out = (float*)d_out;

  float* ws = (float*)d_ws;
  float2* ctab = (float2*)ws;              // 65536 float2, layout [j][l]
  unsigned short* us = (unsigned short*)(ws + 131072);
  unsigned short* Qb = us;                 // 4,194,304 bf16 each
  unsigned short* Kb = Qb + 4194304;
  unsigned short* Vt = Kb + 4194304;
  unsigned short* Og = Vt + 4194304;
  unsigned short* xb = Og + 4194304;       // 4,194,304
  unsigned short* wqkvb = xb + 4194304;    // 3,145,728
  unsigned short* woutb = wqkvb + 3145728; // 1,048,576

  glue_pre_k<<<4352, 256, 0, stream>>>(x, w_qkv, w_out, xb, wqkvb, woutb, ctab);

  gemm_qkv_fused_k<<<768, 256, 0, stream>>>(xb, wqkvb, b_qkv, ctab, Qb, Kb, Vt);

  attn_mfma_k<<<B_SZ * NH * 16, 256, 0, stream>>>(Qb, Kb, Vt, Og);

  gemm_out_k<<<512, 256, 0, stream>>>(Og, woutb, b_out, out, 4096, 1024, 1024);
}

// Round 19
// 106.436 us; speedup vs baseline: 1.1246x; 1.1246x over previous
//
#include <hip/hip_runtime.h>
#include <math.h>

#define B_SZ 2
#define L_SEQ 2048
#define H_SZ 1024
#define NH 16
#define HD 64
#define QSCALE 0.18033688011112042f   // 0.125 * log2(e): S in log2 domain

typedef __attribute__((ext_vector_type(8))) short frag_ab;      // 8 bf16 = 4 VGPR
typedef __attribute__((ext_vector_type(4))) float frag_cd;      // 4 f32 acc
typedef __attribute__((ext_vector_type(8))) unsigned short u16x8;
typedef __attribute__((ext_vector_type(4))) unsigned short u16x4;

__device__ __forceinline__ unsigned short f2bf(float f) {
  unsigned int x = __builtin_bit_cast(unsigned int, f);
  x += 0x7fffu + ((x >> 16) & 1u);          // RNE
  return (unsigned short)(x >> 16);
}
__device__ __forceinline__ float bf2f(unsigned int u) {
  return __builtin_bit_cast(float, u << 16);
}
__device__ __forceinline__ unsigned int cvt_pk_bf16(float lo, float hi) {
  unsigned int r;
  asm("v_cvt_pk_bf16_f32 %0, %1, %2" : "=v"(r) : "v"(lo), "v"(hi));
  return r;
}
// async global->LDS, 16B per lane; LDS dest must be linear in lane order
__device__ __forceinline__ void gload16(const void* g, void* l) {
  __builtin_amdgcn_global_load_lds((const __attribute__((address_space(1))) void*)g,
                                   (__attribute__((address_space(3))) void*)l, 16, 0, 0);
}

__device__ __forceinline__ void cvt8(const float* __restrict__ in,
                                     unsigned short* __restrict__ out, int i) {
  float4 a = *(const float4*)&in[i];
  float4 b = *(const float4*)&in[i + 4];
  u16x8 o = {f2bf(a.x), f2bf(a.y), f2bf(a.z), f2bf(a.w),
             f2bf(b.x), f2bf(b.y), f2bf(b.z), f2bf(b.w)};
  *(u16x8*)&out[i] = o;
}

// BK=32 LDS bank-quad swizzle (R16-validated: conflicts 3.1M -> 0)
#define SWZ32(row) ((((row) >> 1) & 3) << 3)

// ---------------------------------------------------------------------------
// glue_pre: [0,256) rope table TRANSPOSED [j][l] | [256,2304) cvt x
//         | [2304,3840) cvt w_qkv | [3840,4352) cvt w_out.
// ---------------------------------------------------------------------------
__global__ __launch_bounds__(256) void glue_pre_k(
    const float* __restrict__ x, const float* __restrict__ wq, const float* __restrict__ wo,
    unsigned short* __restrict__ xb, unsigned short* __restrict__ wqb,
    unsigned short* __restrict__ wob, float2* __restrict__ ctab) {
  int bx = blockIdx.x, tid = threadIdx.x;
  if (bx < 256) {
    int idx = bx * 256 + tid;          // idx = j*2048 + l
    int j = idx >> 11, l = idx & 2047;
    int ti = l >> 8;
    int s = l & 255;
    float ang_s;
    if (j < 16) ang_s = (float)(s & 15) * powf(10000.f, -(float)j / 16.f);
    else        ang_s = (float)(s >> 4) * powf(10000.f, -(float)(j - 16) / 16.f);
    float ang_t = (float)ti * powf(10000.f, -(float)j / 32.f);
    float a = ang_s + ang_t;
    ctab[idx] = make_float2(cosf(a), sinf(a));
  } else if (bx < 2304) {
    cvt8(x, xb, ((bx - 256) * 256 + tid) * 8);
  } else if (bx < 3840) {
    cvt8(wq, wqb, ((bx - 2304) * 256 + tid) * 8);
  } else {
    cvt8(wo, wob, ((bx - 3840) * 256 + tid) * 8);
  }
}

// staging with pre-swizzled global source (linear LDS dest, rule-21 pair)
#define G_ISSUE(k0, bi)                                                        \
  _Pragma("unroll") for (int it = 0; it < 2; ++it) {                           \
    int c = tid + it * 256;                                                    \
    int row = c >> 2, e0 = ((c & 3) * 8) ^ SWZ32(row);                         \
    gload16(A + (size_t)(m0 + row) * K + (k0) + e0, &As[bi][c * 8]);           \
    gload16(W + (size_t)(n0 + row) * K + (k0) + e0, &Ws[bi][c * 8]);           \
  }

// ---------------------------------------------------------------------------
// Fused QKV GEMM (R16 form, bench-validated best: 42 us, VGPR 80).
// Outputs: Qb,Kb [b][n][l][d] (q pre-scaled by QSCALE), Vt [b][n][d][l].
// ---------------------------------------------------------------------------
__global__ __launch_bounds__(256) void gemm_qkv_fused_k(
    const unsigned short* __restrict__ A, const unsigned short* __restrict__ W,
    const float* __restrict__ bias, const float2* __restrict__ ctab,
    unsigned short* __restrict__ Qb, unsigned short* __restrict__ Kb,
    unsigned short* __restrict__ Vt) {
  const int K = 1024, N = 3072;
  __shared__ unsigned short As[2][128 * 32];
  __shared__ unsigned short Ws[2][128 * 32];
  const frag_cd fzero = {0.f, 0.f, 0.f, 0.f};
  int tid = threadIdx.x;
  int nbx = N >> 7;
  int nwg = gridDim.x;
  int bid = blockIdx.x;
  int qq = nwg >> 3;
  int bidx = (bid & 7) * qq + (bid >> 3);    // bijective XCD-contiguous remap
  int m0 = (bidx / nbx) * 128, n0 = (bidx % nbx) * 128;
  int w = tid >> 6, lane = tid & 63, t = lane & 15, g = lane >> 4;
  int wm = w >> 1, wn = w & 1;
  int fsw = (8 * g) ^ SWZ32(t);              // frag elem offset
  frag_cd acc[4][4];
#pragma unroll
  for (int mi = 0; mi < 4; ++mi)
#pragma unroll
    for (int ni = 0; ni < 4; ++ni) acc[mi][ni] = fzero;

  G_ISSUE(0, 0);
  __syncthreads();
  int kb = 0;
  for (int k0 = 0; k0 < K; k0 += 32, kb ^= 1) {
    if (k0 + 32 < K) { G_ISSUE(k0 + 32, kb ^ 1); }
    frag_ab af[4], wf[4];
#pragma unroll
    for (int mi = 0; mi < 4; ++mi)
      af[mi] = *(const frag_ab*)&As[kb][(wm * 64 + mi * 16 + t) * 32 + fsw];
#pragma unroll
    for (int ni = 0; ni < 4; ++ni)
      wf[ni] = *(const frag_ab*)&Ws[kb][(wn * 64 + ni * 16 + t) * 32 + fsw];
    __builtin_amdgcn_s_setprio(1);
#pragma unroll
    for (int mi = 0; mi < 4; ++mi)
#pragma unroll
      for (int ni = 0; ni < 4; ++ni)
        acc[mi][ni] = __builtin_amdgcn_mfma_f32_16x16x32_bf16(af[mi], wf[ni], acc[mi][ni], 0, 0, 0);
    __builtin_amdgcn_s_setprio(0);
    __syncthreads();
  }

  // fused epilogue (direct stores)
#pragma unroll
  for (int ni = 0; ni < 4; ++ni) {
    int cb = n0 + wn * 64 + ni * 16;        // 16-aligned -> single region
    int region = (cb >> 6) % 3;             // 0=q 1=k 2=v
    int head = cb / 192;
    int d = (cb & 63) + t;
    float bv = bias[cb + t];
    if (region == 2) {
#pragma unroll
      for (int mi = 0; mi < 4; ++mi) {
        int row0 = m0 + wm * 64 + mi * 16 + g * 4;
        int bb = row0 >> 11, l0 = row0 & 2047;
        u16x4 ov;
#pragma unroll
        for (int r = 0; r < 4; ++r) ov[r] = f2bf(acc[mi][ni][r] + bv);
        *(u16x4*)&Vt[((size_t)((bb * NH + head) * HD + d)) * L_SEQ + l0] = ov;
      }
    } else {
      float qs = (region == 0) ? QSCALE : 1.f;
      float sgn = (t & 1) ? qs : -qs;       // odd lane: +s, even lane: -s
      unsigned short* dst = (region == 0) ? Qb : Kb;
      int j = d >> 1;
#pragma unroll
      for (int mi = 0; mi < 4; ++mi) {
        int row0 = m0 + wm * 64 + mi * 16 + g * 4;
        int bb = row0 >> 11, l0 = row0 & 2047;
        size_t obase = ((size_t)(bb * NH + head) * L_SEQ + l0) * HD + d;
        const float2* cp = ctab + (size_t)j * 2048 + l0;   // [j][l], l0 4-aligned
        float4 v01 = *(const float4*)cp;                   // (c0,s0,c1,s1)
        float4 v23 = *(const float4*)(cp + 2);             // (c2,s2,c3,s3)
        float cvec[4] = {v01.x, v01.z, v23.x, v23.z};
        float svec[4] = {v01.y, v01.w, v23.y, v23.w};
#pragma unroll
        for (int r = 0; r < 4; ++r) {
          float v = acc[mi][ni][r] + bv;
          float p = __shfl_xor(v, 1);
          float o = v * (cvec[r] * qs) + p * (svec[r] * sgn);
          dst[obase + (size_t)r * HD] = f2bf(o);
        }
      }
    }
  }
}

// ---------------------------------------------------------------------------
// Out-projection GEMM, 64x128 tile (grid 512 = 2 blocks/CU), fp32 out.
// ---------------------------------------------------------------------------
__global__ __launch_bounds__(256) void gemm_out_k(
    const unsigned short* __restrict__ A, const unsigned short* __restrict__ W,
    const float* __restrict__ bias, float* __restrict__ C, int M, int N, int K) {
  __shared__ unsigned short As[2][64 * 32];
  __shared__ unsigned short Ws[2][128 * 32];
  const frag_cd fzero = {0.f, 0.f, 0.f, 0.f};
  int tid = threadIdx.x;
  int nbx = N >> 7;
  int nwg = gridDim.x;
  int bid = blockIdx.x;
  int qq = nwg >> 3;
  int bidx = (bid & 7) * qq + (bid >> 3);
  int m0 = (bidx / nbx) * 64, n0 = (bidx % nbx) * 128;
  int w = tid >> 6, lane = tid & 63, t = lane & 15, g = lane >> 4;
  int wm = w >> 1, wn = w & 1;
  int fsw = (8 * g) ^ SWZ32(t);
  frag_cd acc[2][4];
#pragma unroll
  for (int mi = 0; mi < 2; ++mi)
#pragma unroll
    for (int ni = 0; ni < 4; ++ni) acc[mi][ni] = fzero;

#define G_ISSUE2(k0, bi)                                                       \
  {                                                                            \
    int rowA = tid >> 2, e0A = ((tid & 3) * 8) ^ SWZ32(rowA);                  \
    gload16(A + (size_t)(m0 + rowA) * K + (k0) + e0A, &As[bi][tid * 8]);       \
    _Pragma("unroll") for (int it = 0; it < 2; ++it) {                         \
      int c = tid + it * 256;                                                  \
      int row = c >> 2, e0 = ((c & 3) * 8) ^ SWZ32(row);                       \
      gload16(W + (size_t)(n0 + row) * K + (k0) + e0, &Ws[bi][c * 8]);         \
    }                                                                          \
  }

  G_ISSUE2(0, 0);
  __syncthreads();
  int kb = 0;
  for (int k0 = 0; k0 < K; k0 += 32, kb ^= 1) {
    if (k0 + 32 < K) { G_ISSUE2(k0 + 32, kb ^ 1); }
    frag_ab af[2], wf[4];
#pragma unroll
    for (int mi = 0; mi < 2; ++mi)
      af[mi] = *(const frag_ab*)&As[kb][(wm * 32 + mi * 16 + t) * 32 + fsw];
#pragma unroll
    for (int ni = 0; ni < 4; ++ni)
      wf[ni] = *(const frag_ab*)&Ws[kb][(wn * 64 + ni * 16 + t) * 32 + fsw];
    __builtin_amdgcn_s_setprio(1);
#pragma unroll
    for (int mi = 0; mi < 2; ++mi)
#pragma unroll
      for (int ni = 0; ni < 4; ++ni)
        acc[mi][ni] = __builtin_amdgcn_mfma_f32_16x16x32_bf16(af[mi], wf[ni], acc[mi][ni], 0, 0, 0);
    __builtin_amdgcn_s_setprio(0);
    __syncthreads();
  }
#pragma unroll
  for (int mi = 0; mi < 2; ++mi)
#pragma unroll
    for (int ni = 0; ni < 4; ++ni) {
      int col = n0 + wn * 64 + ni * 16 + t;
      float bv = bias[col];
#pragma unroll
      for (int r = 0; r < 4; ++r)
        C[(size_t)(m0 + wm * 32 + mi * 16 + g * 4 + r) * N + col] = acc[mi][ni][r] + bv;
    }
}

// ---------------------------------------------------------------------------
// MFMA flash attention (causal), DUAL-CHAIN 4-wave blocks (R17 green form):
// wave w owns rows w*16 of BOTH tiles qtB=31-qtA (L) and qtA (S); shared
// K/V stage; separate PsL/PsS; write-early staging; fixed-C softmax;
// deferred l-reduce. Grid 512.
// ---------------------------------------------------------------------------
__global__ __launch_bounds__(256) void attn_mfma_k(
    const unsigned short* __restrict__ Qg, const unsigned short* __restrict__ Kg,
    const unsigned short* __restrict__ Vt, unsigned short* __restrict__ Og) {
  __shared__ unsigned short Ks[2][64 * 64];
  __shared__ unsigned short Vs[2][64 * 64];
  __shared__ unsigned short PsL[4][16 * 64];
  __shared__ unsigned short PsS[4][16 * 64];
  const frag_cd fzero = {0.f, 0.f, 0.f, 0.f};
  const frag_cd cinit = {-32.f, -32.f, -32.f, -32.f};
  int bx = blockIdx.x;
  int qtA = bx & 15;
  int n = (bx >> 4) & 15;
  int b = bx >> 8;
  int qtB = 31 - qtA;
  int tid = threadIdx.x;
  int w = tid >> 6, lane = tid & 63, t = lane & 15, g = lane >> 4;
  size_t kvbase = ((size_t)(b * NH + n)) * L_SEQ * HD;
  int qrowL = qtB * 64 + w * 16 + t;
  int qrowS = qtA * 64 + w * 16 + t;
  unsigned short* pwL = &PsL[w][0];
  unsigned short* pwS = &PsS[w][0];

  const unsigned short* qpL = Qg + kvbase + (size_t)qrowL * HD;
  const unsigned short* qpS = Qg + kvbase + (size_t)qrowS * HD;
  frag_ab qfL0 = *(const frag_ab*)(qpL + 8 * g), qfL1 = *(const frag_ab*)(qpL + 32 + 8 * g);
  frag_ab qfS0 = *(const frag_ab*)(qpS + 8 * g), qfS1 = *(const frag_ab*)(qpS + 32 + 8 * g);

  frag_cd oaccL[4], oaccS[4];
#pragma unroll
  for (int db = 0; db < 4; ++db) { oaccL[db] = fzero; oaccS[db] = fzero; }
  float lLp = 0.f, lSp = 0.f;

  // staging: 256 threads, two 16B K chunks + two 16B V chunks each
  int srow = tid >> 3, se0 = (tid & 7) * 8;
  int sd0 = (srow * 64 + se0) ^ ((srow & 7) << 3);
  int sd1 = ((srow + 32) * 64 + se0) ^ ((srow & 7) << 3);
  u16x8 kreg0 = *(const u16x8*)(Kg + kvbase + (size_t)srow * HD + se0);
  u16x8 kreg1 = *(const u16x8*)(Kg + kvbase + (size_t)(srow + 32) * HD + se0);
  u16x8 vreg0 = *(const u16x8*)(Vt + kvbase + (size_t)srow * L_SEQ + se0);
  u16x8 vreg1 = *(const u16x8*)(Vt + kvbase + (size_t)(srow + 32) * L_SEQ + se0);
  *(u16x8*)&Ks[0][sd0] = kreg0;
  *(u16x8*)&Ks[0][sd1] = kreg1;
  *(u16x8*)&Vs[0][sd0] = vreg0;
  *(u16x8*)&Vs[0][sd1] = vreg1;
  if (qtB > 0) {
    kreg0 = *(const u16x8*)(Kg + kvbase + (size_t)(64 + srow) * HD + se0);
    kreg1 = *(const u16x8*)(Kg + kvbase + (size_t)(96 + srow) * HD + se0);
    vreg0 = *(const u16x8*)(Vt + kvbase + (size_t)srow * L_SEQ + 64 + se0);
    vreg1 = *(const u16x8*)(Vt + kvbase + (size_t)(srow + 32) * L_SEQ + 64 + se0);
  }

  for (int kt = 0; kt <= qtB; ++kt) {
    int cur = kt & 1, nxt = cur ^ 1;
    __syncthreads();
    if (kt < qtB) {                       // write-early: stage kt+1 at phase top
      *(u16x8*)&Ks[nxt][sd0] = kreg0;
      *(u16x8*)&Ks[nxt][sd1] = kreg1;
      *(u16x8*)&Vs[nxt][sd0] = vreg0;
      *(u16x8*)&Vs[nxt][sd1] = vreg1;
    }
    if (kt + 1 < qtB) {                   // issue loads for kt+2 (hide under compute)
      kreg0 = *(const u16x8*)(Kg + kvbase + (size_t)((kt + 2) * 64 + srow) * HD + se0);
      kreg1 = *(const u16x8*)(Kg + kvbase + (size_t)((kt + 2) * 64 + 32 + srow) * HD + se0);
      vreg0 = *(const u16x8*)(Vt + kvbase + (size_t)srow * L_SEQ + (kt + 2) * 64 + se0);
      vreg1 = *(const u16x8*)(Vt + kvbase + (size_t)(srow + 32) * L_SEQ + (kt + 2) * 64 + se0);
    }
    bool doS = (kt <= qtA);

    // shared K fragments
    frag_ab k0f[4], k1f[4];
#pragma unroll
    for (int kb = 0; kb < 4; ++kb) {
      k0f[kb] = *(const frag_ab*)&Ks[cur][(((kb * 16 + t) * 64) + 8 * g) ^ ((t & 7) << 3)];
      k1f[kb] = *(const frag_ab*)&Ks[cur][(((kb * 16 + t) * 64) + 32 + 8 * g) ^ ((t & 7) << 3)];
    }
    // QK for both chains (independent MFMA streams)
    frag_cd stL[4], stS[4];
    __builtin_amdgcn_s_setprio(1);
#pragma unroll
    for (int kb = 0; kb < 4; ++kb) {
      stL[kb] = __builtin_amdgcn_mfma_f32_16x16x32_bf16(k0f[kb], qfL0, cinit, 0, 0, 0);
      stL[kb] = __builtin_amdgcn_mfma_f32_16x16x32_bf16(k1f[kb], qfL1, stL[kb], 0, 0, 0);
    }
    if (doS) {
#pragma unroll
      for (int kb = 0; kb < 4; ++kb) {
        stS[kb] = __builtin_amdgcn_mfma_f32_16x16x32_bf16(k0f[kb], qfS0, cinit, 0, 0, 0);
        stS[kb] = __builtin_amdgcn_mfma_f32_16x16x32_bf16(k1f[kb], qfS1, stS[kb], 0, 0, 0);
      }
    }
    __builtin_amdgcn_s_setprio(0);

    // V fragments issue early (latency under softmax VALU)
    frag_ab v0f[4], v1f[4];
#pragma unroll
    for (int db = 0; db < 4; ++db) {
      v0f[db] = *(const frag_ab*)&Vs[cur][(((db * 16 + t) * 64) + 8 * g) ^ ((t & 7) << 3)];
      v1f[db] = *(const frag_ab*)&Vs[cur][(((db * 16 + t) * 64) + 32 + 8 * g) ^ ((t & 7) << 3)];
    }

    // softmax L -> PsL
    {
      bool diag = (kt == qtB);
      unsigned int pk[8];
#pragma unroll
      for (int i = 0; i < 8; ++i) {
        int kb = i >> 1, r0 = (2 * i) & 3;
        float x0 = stL[kb][r0], x1 = stL[kb][r0 + 1];
        if (diag) {
          if ((kt * 64 + kb * 16 + g * 4 + r0) > qrowL) x0 = -1e30f;
          if ((kt * 64 + kb * 16 + g * 4 + r0 + 1) > qrowL) x1 = -1e30f;
        }
        float p0 = __builtin_amdgcn_exp2f(x0);
        float p1 = __builtin_amdgcn_exp2f(x1);
        lLp += p0 + p1;
        pk[i] = cvt_pk_bf16(p0, p1);
      }
#pragma unroll
      for (int kb = 0; kb < 4; ++kb) {
        uint2 pr = {pk[kb * 2], pk[kb * 2 + 1]};
        *(uint2*)&pwL[(t * 64 + kb * 16 + g * 4) ^ ((t & 7) << 3)] = pr;
      }
    }
    // softmax S -> PsS (overlaps pwL read latency below)
    if (doS) {
      bool diag = (kt == qtA);
      unsigned int pk[8];
#pragma unroll
      for (int i = 0; i < 8; ++i) {
        int kb = i >> 1, r0 = (2 * i) & 3;
        float x0 = stS[kb][r0], x1 = stS[kb][r0 + 1];
        if (diag) {
          if ((kt * 64 + kb * 16 + g * 4 + r0) > qrowS) x0 = -1e30f;
          if ((kt * 64 + kb * 16 + g * 4 + r0 + 1) > qrowS) x1 = -1e30f;
        }
        float p0 = __builtin_amdgcn_exp2f(x0);
        float p1 = __builtin_amdgcn_exp2f(x1);
        lSp += p0 + p1;
        pk[i] = cvt_pk_bf16(p0, p1);
      }
#pragma unroll
      for (int kb = 0; kb < 4; ++kb) {
        uint2 pr = {pk[kb * 2], pk[kb * 2 + 1]};
        *(uint2*)&pwS[(t * 64 + kb * 16 + g * 4) ^ ((t & 7) << 3)] = pr;
      }
    }

    // PV_L (pfS read latency hides under these MFMAs)
    {
      frag_ab pf0 = *(const frag_ab*)&pwL[(t * 64 + 8 * g) ^ ((t & 7) << 3)];
      frag_ab pf1 = *(const frag_ab*)&pwL[(t * 64 + 32 + 8 * g) ^ ((t & 7) << 3)];
      __builtin_amdgcn_s_setprio(1);
#pragma unroll
      for (int db = 0; db < 4; ++db) {
        oaccL[db] = __builtin_amdgcn_mfma_f32_16x16x32_bf16(v0f[db], pf0, oaccL[db], 0, 0, 0);
        oaccL[db] = __builtin_amdgcn_mfma_f32_16x16x32_bf16(v1f[db], pf1, oaccL[db], 0, 0, 0);
      }
      __builtin_amdgcn_s_setprio(0);
    }
    if (doS) {
      frag_ab pf0 = *(const frag_ab*)&pwS[(t * 64 + 8 * g) ^ ((t & 7) << 3)];
      frag_ab pf1 = *(const frag_ab*)&pwS[(t * 64 + 32 + 8 * g) ^ ((t & 7) << 3)];
      __builtin_amdgcn_s_setprio(1);
#pragma unroll
      for (int db = 0; db < 4; ++db) {
        oaccS[db] = __builtin_amdgcn_mfma_f32_16x16x32_bf16(v0f[db], pf0, oaccS[db], 0, 0, 0);
        oaccS[db] = __builtin_amdgcn_mfma_f32_16x16x32_bf16(v1f[db], pf1, oaccS[db], 0, 0, 0);
      }
      __builtin_amdgcn_s_setprio(0);
    }
  }

  // epilogue: deferred l reduce, o = silu(O/l), both chains
  size_t ob0 = (size_t)b * L_SEQ * H_SZ + n * 64;
#pragma unroll
  for (int side = 0; side < 2; ++side) {
    float lp = side ? lSp : lLp;
    float l_run = lp + __shfl_xor(lp, 16);
    l_run += __shfl_xor(l_run, 32);
    float inv = 1.f / l_run;
    frag_cd* oacc = side ? oaccS : oaccL;
    int qrow = side ? qrowS : qrowL;
#pragma unroll
    for (int db = 0; db < 4; ++db) {
      u16x4 ov;
#pragma unroll
      for (int r = 0; r < 4; ++r) {
        float o = oacc[db][r] * inv;
        o = o / (1.f + __expf(-o));
        ov[r] = f2bf(o);
      }
      *(u16x4*)&Og[ob0 + (size_t)qrow * H_SZ + db * 16 + g * 4] = ov;
    }
  }
}

// ---------------------------------------------------------------------------
extern "C" void kernel_launch(void* const* d_in, const int* in_sizes, int n_in,
                              void* d_out, int out_size, void* d_ws, size_t ws_size,
                              hipStream_t stream) {
  const float* x = (const float*)d_in[0];
  const float* w_qkv = (const float*)d_in[1];
  const float* b_qkv = (const float*)d_in[2];
  const float* w_out = (const float*)d_in[3];
  const float* b_out = (const float*)d_in[4];
  float* out = (float*)d_out;

  float* ws = (float*)d_ws;
  float2* ctab = (float2*)ws;              // 65536 float2, layout [j][l]
  unsigned short* us = (unsigned short*)(ws + 131072);
  unsigned short* Qb = us;                 // 4,194,304 bf16 each
  unsigned short* Kb = Qb + 4194304;
  unsigned short* Vt = Kb + 4194304;
  unsigned short* Og = Vt + 4194304;
  unsigned short* xb = Og + 4194304;       // 4,194,304
  unsigned short* wqkvb = xb + 4194304;    // 3,145,728
  unsigned short* woutb = wqkvb + 3145728; // 1,048,576

  glue_pre_k<<<4352, 256, 0, stream>>>(x, w_qkv, w_out, xb, wqkvb, woutb, ctab);

  gemm_qkv_fused_k<<<768, 256, 0, stream>>>(xb, wqkvb, b_qkv, ctab, Qb, Kb, Vt);

  attn_mfma_k<<<B_SZ * NH * 16, 256, 0, stream>>>(Qb, Kb, Vt, Og);

  gemm_out_k<<<512, 256, 0, stream>>>(Og, woutb, b_out, out, 4096, 1024, 1024);
}

// Round 20
// 106.065 us; speedup vs baseline: 1.1286x; 1.0035x over previous
//
#include <hip/hip_runtime.h>
#include <math.h>

#define B_SZ 2
#define L_SEQ 2048
#define H_SZ 1024
#define NH 16
#define HD 64
#define QSCALE 0.18033688011112042f   // 0.125 * log2(e): S in log2 domain

typedef __attribute__((ext_vector_type(8))) short frag_ab;      // 8 bf16 = 4 VGPR
typedef __attribute__((ext_vector_type(4))) float frag_cd;      // 4 f32 acc
typedef __attribute__((ext_vector_type(8))) unsigned short u16x8;
typedef __attribute__((ext_vector_type(4))) unsigned short u16x4;

__device__ __forceinline__ unsigned short f2bf(float f) {
  unsigned int x = __builtin_bit_cast(unsigned int, f);
  x += 0x7fffu + ((x >> 16) & 1u);          // RNE
  return (unsigned short)(x >> 16);
}
__device__ __forceinline__ float bf2f(unsigned int u) {
  return __builtin_bit_cast(float, u << 16);
}
__device__ __forceinline__ unsigned int cvt_pk_bf16(float lo, float hi) {
  unsigned int r;
  asm("v_cvt_pk_bf16_f32 %0, %1, %2" : "=v"(r) : "v"(lo), "v"(hi));
  return r;
}
// async global->LDS, 16B per lane; LDS dest must be linear in lane order
__device__ __forceinline__ void gload16(const void* g, void* l) {
  __builtin_amdgcn_global_load_lds((const __attribute__((address_space(1))) void*)g,
                                   (__attribute__((address_space(3))) void*)l, 16, 0, 0);
}

__device__ __forceinline__ void cvt8(const float* __restrict__ in,
                                     unsigned short* __restrict__ out, int i) {
  float4 a = *(const float4*)&in[i];
  float4 b = *(const float4*)&in[i + 4];
  u16x8 o = {f2bf(a.x), f2bf(a.y), f2bf(a.z), f2bf(a.w),
             f2bf(b.x), f2bf(b.y), f2bf(b.z), f2bf(b.w)};
  *(u16x8*)&out[i] = o;
}

// BK=32 LDS bank-quad swizzle (R16-validated: conflicts 3.1M -> 0)
#define SWZ32(row) ((((row) >> 1) & 3) << 3)

// ---------------------------------------------------------------------------
// glue_pre: [0,256) rope table TRANSPOSED [j][l] | [256,2304) cvt x
//         | [2304,3840) cvt w_qkv | [3840,4352) cvt w_out.
// ---------------------------------------------------------------------------
__global__ __launch_bounds__(256) void glue_pre_k(
    const float* __restrict__ x, const float* __restrict__ wq, const float* __restrict__ wo,
    unsigned short* __restrict__ xb, unsigned short* __restrict__ wqb,
    unsigned short* __restrict__ wob, float2* __restrict__ ctab) {
  int bx = blockIdx.x, tid = threadIdx.x;
  if (bx < 256) {
    int idx = bx * 256 + tid;          // idx = j*2048 + l
    int j = idx >> 11, l = idx & 2047;
    int ti = l >> 8;
    int s = l & 255;
    float ang_s;
    if (j < 16) ang_s = (float)(s & 15) * powf(10000.f, -(float)j / 16.f);
    else        ang_s = (float)(s >> 4) * powf(10000.f, -(float)(j - 16) / 16.f);
    float ang_t = (float)ti * powf(10000.f, -(float)j / 32.f);
    float a = ang_s + ang_t;
    ctab[idx] = make_float2(cosf(a), sinf(a));
  } else if (bx < 2304) {
    cvt8(x, xb, ((bx - 256) * 256 + tid) * 8);
  } else if (bx < 3840) {
    cvt8(wq, wqb, ((bx - 2304) * 256 + tid) * 8);
  } else {
    cvt8(wo, wob, ((bx - 3840) * 256 + tid) * 8);
  }
}

// staging with pre-swizzled global source (linear LDS dest, rule-21 pair)
#define G_ISSUE(k0, bi)                                                        \
  _Pragma("unroll") for (int it = 0; it < 2; ++it) {                           \
    int c = tid + it * 256;                                                    \
    int row = c >> 2, e0 = ((c & 3) * 8) ^ SWZ32(row);                         \
    gload16(A + (size_t)(m0 + row) * K + (k0) + e0, &As[bi][c * 8]);           \
    gload16(W + (size_t)(n0 + row) * K + (k0) + e0, &Ws[bi][c * 8]);           \
  }

// ---------------------------------------------------------------------------
// Fused QKV GEMM (R16 form, bench-validated best: 42 us, VGPR 80).
// Outputs: Qb,Kb [b][n][l][d] (q pre-scaled by QSCALE), Vt [b][n][d][l].
// ---------------------------------------------------------------------------
__global__ __launch_bounds__(256) void gemm_qkv_fused_k(
    const unsigned short* __restrict__ A, const unsigned short* __restrict__ W,
    const float* __restrict__ bias, const float2* __restrict__ ctab,
    unsigned short* __restrict__ Qb, unsigned short* __restrict__ Kb,
    unsigned short* __restrict__ Vt) {
  const int K = 1024, N = 3072;
  __shared__ unsigned short As[2][128 * 32];
  __shared__ unsigned short Ws[2][128 * 32];
  const frag_cd fzero = {0.f, 0.f, 0.f, 0.f};
  int tid = threadIdx.x;
  int nbx = N >> 7;
  int nwg = gridDim.x;
  int bid = blockIdx.x;
  int qq = nwg >> 3;
  int bidx = (bid & 7) * qq + (bid >> 3);    // bijective XCD-contiguous remap
  int m0 = (bidx / nbx) * 128, n0 = (bidx % nbx) * 128;
  int w = tid >> 6, lane = tid & 63, t = lane & 15, g = lane >> 4;
  int wm = w >> 1, wn = w & 1;
  int fsw = (8 * g) ^ SWZ32(t);              // frag elem offset
  frag_cd acc[4][4];
#pragma unroll
  for (int mi = 0; mi < 4; ++mi)
#pragma unroll
    for (int ni = 0; ni < 4; ++ni) acc[mi][ni] = fzero;

  G_ISSUE(0, 0);
  __syncthreads();
  int kb = 0;
  for (int k0 = 0; k0 < K; k0 += 32, kb ^= 1) {
    if (k0 + 32 < K) { G_ISSUE(k0 + 32, kb ^ 1); }
    frag_ab af[4], wf[4];
#pragma unroll
    for (int mi = 0; mi < 4; ++mi)
      af[mi] = *(const frag_ab*)&As[kb][(wm * 64 + mi * 16 + t) * 32 + fsw];
#pragma unroll
    for (int ni = 0; ni < 4; ++ni)
      wf[ni] = *(const frag_ab*)&Ws[kb][(wn * 64 + ni * 16 + t) * 32 + fsw];
    __builtin_amdgcn_s_setprio(1);
#pragma unroll
    for (int mi = 0; mi < 4; ++mi)
#pragma unroll
      for (int ni = 0; ni < 4; ++ni)
        acc[mi][ni] = __builtin_amdgcn_mfma_f32_16x16x32_bf16(af[mi], wf[ni], acc[mi][ni], 0, 0, 0);
    __builtin_amdgcn_s_setprio(0);
    __syncthreads();
  }

  // fused epilogue (direct stores)
#pragma unroll
  for (int ni = 0; ni < 4; ++ni) {
    int cb = n0 + wn * 64 + ni * 16;        // 16-aligned -> single region
    int region = (cb >> 6) % 3;             // 0=q 1=k 2=v
    int head = cb / 192;
    int d = (cb & 63) + t;
    float bv = bias[cb + t];
    if (region == 2) {
#pragma unroll
      for (int mi = 0; mi < 4; ++mi) {
        int row0 = m0 + wm * 64 + mi * 16 + g * 4;
        int bb = row0 >> 11, l0 = row0 & 2047;
        u16x4 ov;
#pragma unroll
        for (int r = 0; r < 4; ++r) ov[r] = f2bf(acc[mi][ni][r] + bv);
        *(u16x4*)&Vt[((size_t)((bb * NH + head) * HD + d)) * L_SEQ + l0] = ov;
      }
    } else {
      float qs = (region == 0) ? QSCALE : 1.f;
      float sgn = (t & 1) ? qs : -qs;       // odd lane: +s, even lane: -s
      unsigned short* dst = (region == 0) ? Qb : Kb;
      int j = d >> 1;
#pragma unroll
      for (int mi = 0; mi < 4; ++mi) {
        int row0 = m0 + wm * 64 + mi * 16 + g * 4;
        int bb = row0 >> 11, l0 = row0 & 2047;
        size_t obase = ((size_t)(bb * NH + head) * L_SEQ + l0) * HD + d;
        const float2* cp = ctab + (size_t)j * 2048 + l0;   // [j][l], l0 4-aligned
        float4 v01 = *(const float4*)cp;                   // (c0,s0,c1,s1)
        float4 v23 = *(const float4*)(cp + 2);             // (c2,s2,c3,s3)
        float cvec[4] = {v01.x, v01.z, v23.x, v23.z};
        float svec[4] = {v01.y, v01.w, v23.y, v23.w};
#pragma unroll
        for (int r = 0; r < 4; ++r) {
          float v = acc[mi][ni][r] + bv;
          float p = __shfl_xor(v, 1);
          float o = v * (cvec[r] * qs) + p * (svec[r] * sgn);
          dst[obase + (size_t)r * HD] = f2bf(o);
        }
      }
    }
  }
}

// ---------------------------------------------------------------------------
// Out-projection GEMM, 64x128 tile (grid 512 = 2 blocks/CU), fp32 out.
// ---------------------------------------------------------------------------
__global__ __launch_bounds__(256) void gemm_out_k(
    const unsigned short* __restrict__ A, const unsigned short* __restrict__ W,
    const float* __restrict__ bias, float* __restrict__ C, int M, int N, int K) {
  __shared__ unsigned short As[2][64 * 32];
  __shared__ unsigned short Ws[2][128 * 32];
  const frag_cd fzero = {0.f, 0.f, 0.f, 0.f};
  int tid = threadIdx.x;
  int nbx = N >> 7;
  int nwg = gridDim.x;
  int bid = blockIdx.x;
  int qq = nwg >> 3;
  int bidx = (bid & 7) * qq + (bid >> 3);
  int m0 = (bidx / nbx) * 64, n0 = (bidx % nbx) * 128;
  int w = tid >> 6, lane = tid & 63, t = lane & 15, g = lane >> 4;
  int wm = w >> 1, wn = w & 1;
  int fsw = (8 * g) ^ SWZ32(t);
  frag_cd acc[2][4];
#pragma unroll
  for (int mi = 0; mi < 2; ++mi)
#pragma unroll
    for (int ni = 0; ni < 4; ++ni) acc[mi][ni] = fzero;

#define G_ISSUE2(k0, bi)                                                       \
  {                                                                            \
    int rowA = tid >> 2, e0A = ((tid & 3) * 8) ^ SWZ32(rowA);                  \
    gload16(A + (size_t)(m0 + rowA) * K + (k0) + e0A, &As[bi][tid * 8]);       \
    _Pragma("unroll") for (int it = 0; it < 2; ++it) {                         \
      int c = tid + it * 256;                                                  \
      int row = c >> 2, e0 = ((c & 3) * 8) ^ SWZ32(row);                       \
      gload16(W + (size_t)(n0 + row) * K + (k0) + e0, &Ws[bi][c * 8]);         \
    }                                                                          \
  }

  G_ISSUE2(0, 0);
  __syncthreads();
  int kb = 0;
  for (int k0 = 0; k0 < K; k0 += 32, kb ^= 1) {
    if (k0 + 32 < K) { G_ISSUE2(k0 + 32, kb ^ 1); }
    frag_ab af[2], wf[4];
#pragma unroll
    for (int mi = 0; mi < 2; ++mi)
      af[mi] = *(const frag_ab*)&As[kb][(wm * 32 + mi * 16 + t) * 32 + fsw];
#pragma unroll
    for (int ni = 0; ni < 4; ++ni)
      wf[ni] = *(const frag_ab*)&Ws[kb][(wn * 64 + ni * 16 + t) * 32 + fsw];
    __builtin_amdgcn_s_setprio(1);
#pragma unroll
    for (int mi = 0; mi < 2; ++mi)
#pragma unroll
      for (int ni = 0; ni < 4; ++ni)
        acc[mi][ni] = __builtin_amdgcn_mfma_f32_16x16x32_bf16(af[mi], wf[ni], acc[mi][ni], 0, 0, 0);
    __builtin_amdgcn_s_setprio(0);
    __syncthreads();
  }
#pragma unroll
  for (int mi = 0; mi < 2; ++mi)
#pragma unroll
    for (int ni = 0; ni < 4; ++ni) {
      int col = n0 + wn * 64 + ni * 16 + t;
      float bv = bias[col];
#pragma unroll
      for (int r = 0; r < 4; ++r)
        C[(size_t)(m0 + wm * 32 + mi * 16 + g * 4 + r) * N + col] = acc[mi][ni][r] + bv;
    }
}

// ---------------------------------------------------------------------------
// MFMA flash attention (causal), DUAL-CHAIN 4-wave blocks (R17 green form):
// wave w owns rows w*16 of BOTH tiles qtB=31-qtA (L) and qtA (S); shared
// K/V stage; separate PsL/PsS; write-early staging; fixed-C softmax
// P = 2^(S-32) via MFMA C-init; deferred l-reduce. Grid 512.
// ---------------------------------------------------------------------------
__global__ __launch_bounds__(256) void attn_mfma_k(
    const unsigned short* __restrict__ Qg, const unsigned short* __restrict__ Kg,
    const unsigned short* __restrict__ Vt, unsigned short* __restrict__ Og) {
  __shared__ unsigned short Ks[2][64 * 64];
  __shared__ unsigned short Vs[2][64 * 64];
  __shared__ unsigned short PsL[4][16 * 64];
  __shared__ unsigned short PsS[4][16 * 64];
  const frag_cd fzero = {0.f, 0.f, 0.f, 0.f};
  const frag_cd cinit = {-32.f, -32.f, -32.f, -32.f};
  int bx = blockIdx.x;
  int qtA = bx & 15;
  int n = (bx >> 4) & 15;
  int b = bx >> 8;
  int qtB = 31 - qtA;
  int tid = threadIdx.x;
  int w = tid >> 6, lane = tid & 63, t = lane & 15, g = lane >> 4;
  size_t kvbase = ((size_t)(b * NH + n)) * L_SEQ * HD;
  int qrowL = qtB * 64 + w * 16 + t;
  int qrowS = qtA * 64 + w * 16 + t;
  unsigned short* pwL = &PsL[w][0];
  unsigned short* pwS = &PsS[w][0];

  const unsigned short* qpL = Qg + kvbase + (size_t)qrowL * HD;
  const unsigned short* qpS = Qg + kvbase + (size_t)qrowS * HD;
  frag_ab qfL0 = *(const frag_ab*)(qpL + 8 * g), qfL1 = *(const frag_ab*)(qpL + 32 + 8 * g);
  frag_ab qfS0 = *(const frag_ab*)(qpS + 8 * g), qfS1 = *(const frag_ab*)(qpS + 32 + 8 * g);

  frag_cd oaccL[4], oaccS[4];
#pragma unroll
  for (int db = 0; db < 4; ++db) { oaccL[db] = fzero; oaccS[db] = fzero; }
  float lLp = 0.f, lSp = 0.f;

  // staging: 256 threads, two 16B K chunks + two 16B V chunks each
  int srow = tid >> 3, se0 = (tid & 7) * 8;
  int sd0 = (srow * 64 + se0) ^ ((srow & 7) << 3);
  int sd1 = ((srow + 32) * 64 + se0) ^ ((srow & 7) << 3);
  u16x8 kreg0 = *(const u16x8*)(Kg + kvbase + (size_t)srow * HD + se0);
  u16x8 kreg1 = *(const u16x8*)(Kg + kvbase + (size_t)(srow + 32) * HD + se0);
  u16x8 vreg0 = *(const u16x8*)(Vt + kvbase + (size_t)srow * L_SEQ + se0);
  u16x8 vreg1 = *(const u16x8*)(Vt + kvbase + (size_t)(srow + 32) * L_SEQ + se0);
  *(u16x8*)&Ks[0][sd0] = kreg0;
  *(u16x8*)&Ks[0][sd1] = kreg1;
  *(u16x8*)&Vs[0][sd0] = vreg0;
  *(u16x8*)&Vs[0][sd1] = vreg1;
  if (qtB > 0) {
    kreg0 = *(const u16x8*)(Kg + kvbase + (size_t)(64 + srow) * HD + se0);
    kreg1 = *(const u16x8*)(Kg + kvbase + (size_t)(96 + srow) * HD + se0);
    vreg0 = *(const u16x8*)(Vt + kvbase + (size_t)srow * L_SEQ + 64 + se0);
    vreg1 = *(const u16x8*)(Vt + kvbase + (size_t)(srow + 32) * L_SEQ + 64 + se0);
  }

  for (int kt = 0; kt <= qtB; ++kt) {
    int cur = kt & 1, nxt = cur ^ 1;
    __syncthreads();
    if (kt < qtB) {                       // write-early: stage kt+1 at phase top
      *(u16x8*)&Ks[nxt][sd0] = kreg0;
      *(u16x8*)&Ks[nxt][sd1] = kreg1;
      *(u16x8*)&Vs[nxt][sd0] = vreg0;
      *(u16x8*)&Vs[nxt][sd1] = vreg1;
    }
    if (kt + 1 < qtB) {                   // issue loads for kt+2 (hide under compute)
      kreg0 = *(const u16x8*)(Kg + kvbase + (size_t)((kt + 2) * 64 + srow) * HD + se0);
      kreg1 = *(const u16x8*)(Kg + kvbase + (size_t)((kt + 2) * 64 + 32 + srow) * HD + se0);
      vreg0 = *(const u16x8*)(Vt + kvbase + (size_t)srow * L_SEQ + (kt + 2) * 64 + se0);
      vreg1 = *(const u16x8*)(Vt + kvbase + (size_t)(srow + 32) * L_SEQ + (kt + 2) * 64 + se0);
    }
    bool doS = (kt <= qtA);

    // shared K fragments
    frag_ab k0f[4], k1f[4];
#pragma unroll
    for (int kb = 0; kb < 4; ++kb) {
      k0f[kb] = *(const frag_ab*)&Ks[cur][(((kb * 16 + t) * 64) + 8 * g) ^ ((t & 7) << 3)];
      k1f[kb] = *(const frag_ab*)&Ks[cur][(((kb * 16 + t) * 64) + 32 + 8 * g) ^ ((t & 7) << 3)];
    }
    // QK for both chains (independent MFMA streams)
    frag_cd stL[4], stS[4];
    __builtin_amdgcn_s_setprio(1);
#pragma unroll
    for (int kb = 0; kb < 4; ++kb) {
      stL[kb] = __builtin_amdgcn_mfma_f32_16x16x32_bf16(k0f[kb], qfL0, cinit, 0, 0, 0);
      stL[kb] = __builtin_amdgcn_mfma_f32_16x16x32_bf16(k1f[kb], qfL1, stL[kb], 0, 0, 0);
    }
    if (doS) {
#pragma unroll
      for (int kb = 0; kb < 4; ++kb) {
        stS[kb] = __builtin_amdgcn_mfma_f32_16x16x32_bf16(k0f[kb], qfS0, cinit, 0, 0, 0);
        stS[kb] = __builtin_amdgcn_mfma_f32_16x16x32_bf16(k1f[kb], qfS1, stS[kb], 0, 0, 0);
      }
    }
    __builtin_amdgcn_s_setprio(0);

    // V fragments issue early (latency under softmax VALU)
    frag_ab v0f[4], v1f[4];
#pragma unroll
    for (int db = 0; db < 4; ++db) {
      v0f[db] = *(const frag_ab*)&Vs[cur][(((db * 16 + t) * 64) + 8 * g) ^ ((t & 7) << 3)];
      v1f[db] = *(const frag_ab*)&Vs[cur][(((db * 16 + t) * 64) + 32 + 8 * g) ^ ((t & 7) << 3)];
    }

    // softmax L -> PsL
    {
      bool diag = (kt == qtB);
      unsigned int pk[8];
#pragma unroll
      for (int i = 0; i < 8; ++i) {
        int kb = i >> 1, r0 = (2 * i) & 3;
        float x0 = stL[kb][r0], x1 = stL[kb][r0 + 1];
        if (diag) {
          if ((kt * 64 + kb * 16 + g * 4 + r0) > qrowL) x0 = -1e30f;
          if ((kt * 64 + kb * 16 + g * 4 + r0 + 1) > qrowL) x1 = -1e30f;
        }
        float p0 = __builtin_amdgcn_exp2f(x0);
        float p1 = __builtin_amdgcn_exp2f(x1);
        lLp += p0 + p1;
        pk[i] = cvt_pk_bf16(p0, p1);
      }
#pragma unroll
      for (int kb = 0; kb < 4; ++kb) {
        uint2 pr = {pk[kb * 2], pk[kb * 2 + 1]};
        *(uint2*)&pwL[(t * 64 + kb * 16 + g * 4) ^ ((t & 7) << 3)] = pr;
      }
    }
    // softmax S -> PsS (overlaps pwL read latency below)
    if (doS) {
      bool diag = (kt == qtA);
      unsigned int pk[8];
#pragma unroll
      for (int i = 0; i < 8; ++i) {
        int kb = i >> 1, r0 = (2 * i) & 3;
        float x0 = stS[kb][r0], x1 = stS[kb][r0 + 1];
        if (diag) {
          if ((kt * 64 + kb * 16 + g * 4 + r0) > qrowS) x0 = -1e30f;
          if ((kt * 64 + kb * 16 + g * 4 + r0 + 1) > qrowS) x1 = -1e30f;
        }
        float p0 = __builtin_amdgcn_exp2f(x0);
        float p1 = __builtin_amdgcn_exp2f(x1);
        lSp += p0 + p1;
        pk[i] = cvt_pk_bf16(p0, p1);
      }
#pragma unroll
      for (int kb = 0; kb < 4; ++kb) {
        uint2 pr = {pk[kb * 2], pk[kb * 2 + 1]};
        *(uint2*)&pwS[(t * 64 + kb * 16 + g * 4) ^ ((t & 7) << 3)] = pr;
      }
    }

    // PV_L (pfS read latency hides under these MFMAs)
    {
      frag_ab pf0 = *(const frag_ab*)&pwL[(t * 64 + 8 * g) ^ ((t & 7) << 3)];
      frag_ab pf1 = *(const frag_ab*)&pwL[(t * 64 + 32 + 8 * g) ^ ((t & 7) << 3)];
      __builtin_amdgcn_s_setprio(1);
#pragma unroll
      for (int db = 0; db < 4; ++db) {
        oaccL[db] = __builtin_amdgcn_mfma_f32_16x16x32_bf16(v0f[db], pf0, oaccL[db], 0, 0, 0);
        oaccL[db] = __builtin_amdgcn_mfma_f32_16x16x32_bf16(v1f[db], pf1, oaccL[db], 0, 0, 0);
      }
      __builtin_amdgcn_s_setprio(0);
    }
    if (doS) {
      frag_ab pf0 = *(const frag_ab*)&pwS[(t * 64 + 8 * g) ^ ((t & 7) << 3)];
      frag_ab pf1 = *(const frag_ab*)&pwS[(t * 64 + 32 + 8 * g) ^ ((t & 7) << 3)];
      __builtin_amdgcn_s_setprio(1);
#pragma unroll
      for (int db = 0; db < 4; ++db) {
        oaccS[db] = __builtin_amdgcn_mfma_f32_16x16x32_bf16(v0f[db], pf0, oaccS[db], 0, 0, 0);
        oaccS[db] = __builtin_amdgcn_mfma_f32_16x16x32_bf16(v1f[db], pf1, oaccS[db], 0, 0, 0);
      }
      __builtin_amdgcn_s_setprio(0);
    }
  }

  // epilogue: deferred l reduce, o = silu(O/l), both chains
  size_t ob0 = (size_t)b * L_SEQ * H_SZ + n * 64;
#pragma unroll
  for (int side = 0; side < 2; ++side) {
    float lp = side ? lSp : lLp;
    float l_run = lp + __shfl_xor(lp, 16);
    l_run += __shfl_xor(l_run, 32);
    float inv = 1.f / l_run;
    frag_cd* oacc = side ? oaccS : oaccL;
    int qrow = side ? qrowS : qrowL;
#pragma unroll
    for (int db = 0; db < 4; ++db) {
      u16x4 ov;
#pragma unroll
      for (int r = 0; r < 4; ++r) {
        float o = oacc[db][r] * inv;
        o = o / (1.f + __expf(-o));
        ov[r] = f2bf(o);
      }
      *(u16x4*)&Og[ob0 + (size_t)qrow * H_SZ + db * 16 + g * 4] = ov;
    }
  }
}

// ---------------------------------------------------------------------------
extern "C" void kernel_launch(void* const* d_in, const int* in_sizes, int n_in,
                              void* d_out, int out_size, void* d_ws, size_t ws_size,
                              hipStream_t stream) {
  const float* x = (const float*)d_in[0];
  const float* w_qkv = (const float*)d_in[1];
  const float* b_qkv = (const float*)d_in[2];
  const float* w_out = (const float*)d_in[3];
  const float* b_out = (const float*)d_in[4];
  float* out = (float*)d_out;

  float* ws = (float*)d_ws;
  float2* ctab = (float2*)ws;              // 65536 float2, layout [j][l]
  unsigned short* us = (unsigned short*)(ws + 131072);
  unsigned short* Qb = us;                 // 4,194,304 bf16 each
  unsigned short* Kb = Qb + 4194304;
  unsigned short* Vt = Kb + 4194304;
  unsigned short* Og = Vt + 4194304;
  unsigned short* xb = Og + 4194304;       // 4,194,304
  unsigned short* wqkvb = xb + 4194304;    // 3,145,728
  unsigned short* woutb = wqkvb + 3145728; // 1,048,576

  glue_pre_k<<<4352, 256, 0, stream>>>(x, w_qkv, w_out, xb, wqkvb, woutb, ctab);

  gemm_qkv_fused_k<<<768, 256, 0, stream>>>(xb, wqkvb, b_qkv, ctab, Qb, Kb, Vt);

  attn_mfma_k<<<B_SZ * NH * 16, 256, 0, stream>>>(Qb, Kb, Vt, Og);

  gemm_out_k<<<512, 256, 0, stream>>>(Og, woutb, b_out, out, 4096, 1024, 1024);
}